// Round 8
// baseline (7350.764 us; speedup 1.0000x reference)
//
#include <hip/hip_runtime.h>

#define T_SEQ 543
#define B_TOT 2048

typedef _Float16 f16;
typedef f16   f16x8 __attribute__((ext_vector_type(8)));
typedef f16   f16x2 __attribute__((ext_vector_type(2)));
typedef float f32x4 __attribute__((ext_vector_type(4)));

#if defined(__has_builtin)
#if __has_builtin(__builtin_amdgcn_fdot2)
#define HAVE_FDOT2 1
#endif
#if __has_builtin(__builtin_amdgcn_rcpf)
#define RCP(x) __builtin_amdgcn_rcpf(x)
#endif
#endif
#ifndef RCP
#define RCP(x) (1.0f / (x))
#endif

__device__ __forceinline__ float sigm(float x)   { return RCP(1.0f + __expf(-x)); }
__device__ __forceinline__ float tanh_f(float x) { return fmaf(-2.0f, RCP(__expf(2.0f * x) + 1.0f), 1.0f); }

__device__ __forceinline__ f32x4 mfma16(f16x8 a, f16x8 b, f32x4 c) {
    return __builtin_amdgcn_mfma_f32_16x16x32_f16(a, b, c, 0, 0, 0);
}

__device__ __forceinline__ float dot2f(f16x2 a, f16x2 b, float c) {
#ifdef HAVE_FDOT2
    return __builtin_amdgcn_fdot2(a, b, c, false);
#else
    return c + (float)a.x * (float)b.x + (float)a.y * (float)b.y;
#endif
}

union U8 { f16x8 v; f16x2 h[4]; };
__device__ __forceinline__ float dot8(f16x8 a, f16x8 b, float c) {
    U8 A, B; A.v = a; B.v = b;
    c = dot2f(A.h[0], B.h[0], c); c = dot2f(A.h[1], B.h[1], c);
    c = dot2f(A.h[2], B.h[2], c); c = dot2f(A.h[3], B.h[3], c);
    return c;
}

// B-fragment: lane holds w[nrow][k0..k0+8) as f16x8 (row-major fp32 source)
__device__ __forceinline__ f16x8 loadB(const float* __restrict__ g, int nrow, int ldk, int k0) {
    const float* p = g + (size_t)nrow * ldk + k0;
    float4 a = *(const float4*)p;
    float4 b = *(const float4*)(p + 4);
    f16x8 r;
    r[0] = (f16)a.x; r[1] = (f16)a.y; r[2] = (f16)a.z; r[3] = (f16)a.w;
    r[4] = (f16)b.x; r[5] = (f16)b.y; r[6] = (f16)b.z; r[7] = (f16)b.w;
    return r;
}

// ---- LDS layout (bytes). Batch row r lives at tile row 2r; odd rows stay 0. ----
#define L_H1S 0        // 2 bufs x [16][64] f16 = 4096   (raw h1; buf[t&1] = h1(t))
#define L_H2S 4096     // 2 x [16][128]        = 8192    (raw h2; buf[t&1] = h2(t))
#define L_H3S 12288    // 2 x [16][64]         = 4096    (raw h3; buf[(t+1)&1] = h3(t))
#define L_H1R 16384    // [16][64]             = 2048    (relu h1(t))
#define L_H2R 18432    // [16][128]            = 4096    (relu h2(t))
#define L_H3R 22528    // 2 x [16][64]         = 4096    (relu h3; buf[t&1] = h3(t))
#define L_X8  26624    // 2 bufs x 8 rows x 24 f32 = 1536 (x 8-step stage)
#define SMEM_T 28160

// XOR-swizzled LDS accessors (spread row-strided b128 reads over banks)
__device__ __forceinline__ f16x8 ldsA(const unsigned char* sm, int base, int stride, int row, int kByte) {
    int off = (base + row * stride + kByte) ^ ((row & 7) << 4);
    return *(const f16x8*)(sm + off);
}
__device__ __forceinline__ void stH(unsigned char* sm, int base, int stride, int row, int col, f16 v) {
    int off = (base + row * stride + col * 2) ^ ((row & 7) << 4);
    *(f16*)(sm + off) = v;
}

__global__ void cvt_f16(const float* __restrict__ s, f16* __restrict__ d, int n) {
    int i = blockIdx.x * 256 + threadIdx.x;
    if (i < n) d[i] = (f16)s[i];
}

// fused GRU gate; biases pre-folded into the accumulators
__device__ __forceinline__ float gru_cell(float aR, float aZ, float aXn, float aHn, float hprev) {
    float r = sigm(aR);
    float z = sigm(aZ);
    float n = tanh_f(aXn + r * aHn);
    return (1.f - z) * n + z * hprev;
}

template<bool W1H>
__global__ __launch_bounds__(1024, 1) void gru_fused(
    const float* __restrict__ x,
    const float* __restrict__ w_ih1, const float* __restrict__ w_hh1,
    const float* __restrict__ b_ih1, const float* __restrict__ b_hh1,
    const float* __restrict__ w_ih2, const float* __restrict__ w_hh2,
    const float* __restrict__ b_ih2, const float* __restrict__ b_hh2,
    const float* __restrict__ w_ih3, const float* __restrict__ w_hh3,
    const float* __restrict__ b_ih3, const float* __restrict__ b_hh3,
    const f16* __restrict__ w1h, const float* __restrict__ w1, const float* __restrict__ bd1,
    const float* __restrict__ w2, const float* __restrict__ bd2,
    const float* __restrict__ w3, const float* __restrict__ bd3,
    float* __restrict__ out)
{
    __shared__ __align__(16) unsigned char sm[SMEM_T];
    const int tid = threadIdx.x;
    const int Bb  = blockIdx.x * 8;   // 8 batch rows per block
    const int wv  = tid >> 6;         // wave 0..15 (0-7 recurrent, 8-15 helpers)
    const int l   = tid & 63;
    const int lc  = l & 15;           // col index within fragment
    const int lr  = l >> 4;           // k-group; owns tile rows 4lr, 4lr+2

    // zero all LDS once (odd/pad rows must stay zero forever)
    for (int e = tid * 4; e < SMEM_T; e += 1024 * 4) *(float*)(sm + e) = 0.0f;

    // ---- persistent weight fragments (recurrent waves only) ----
    f16x8 b1h[3][2];               // waves 0-3: w_hh1 [192][64]
    f16x8 b3x[3][4], b3h[3][2];    // waves 4-7: w_ih3 [192][128], w_hh3 [192][64]
    f16x8 b2x[3][2], b2h[3][4];    // waves 0-7: w_ih2 [384][64], w_hh2 [384][128]
    float wi1[9];
    float bs1r = 0, bs1z = 0, bi1n = 0, bh1n = 0;
    float bs3r = 0, bs3z = 0, bi3n = 0, bh3n = 0;
    float bs2r = 0, bs2z = 0, bi2n = 0, bh2n = 0;

    const int cj  = (wv & 3) * 16 + lc;   // h-col for L1/L3 phases
    const int cj2 = (wv & 7) * 16 + lc;   // h-col for L2 phase
    if (wv < 4) {
        #pragma unroll
        for (int g = 0; g < 3; ++g)
            #pragma unroll
            for (int kt = 0; kt < 2; ++kt)
                b1h[g][kt] = loadB(w_hh1, g * 64 + cj, 64, kt * 32 + lr * 8);
        bs1r = b_ih1[cj] + b_hh1[cj];
        bs1z = b_ih1[cj + 64] + b_hh1[cj + 64];
        bi1n = b_ih1[cj + 128]; bh1n = b_hh1[cj + 128];
        #pragma unroll
        for (int g = 0; g < 3; ++g)
            #pragma unroll
            for (int i = 0; i < 3; ++i) wi1[g * 3 + i] = w_ih1[(cj + g * 64) * 3 + i];
    } else if (wv < 8) {
        #pragma unroll
        for (int g = 0; g < 3; ++g) {
            #pragma unroll
            for (int kt = 0; kt < 4; ++kt)
                b3x[g][kt] = loadB(w_ih3, g * 64 + cj, 128, kt * 32 + lr * 8);
            #pragma unroll
            for (int kt = 0; kt < 2; ++kt)
                b3h[g][kt] = loadB(w_hh3, g * 64 + cj, 64, kt * 32 + lr * 8);
        }
        bs3r = b_ih3[cj] + b_hh3[cj];
        bs3z = b_ih3[cj + 64] + b_hh3[cj + 64];
        bi3n = b_ih3[cj + 128]; bh3n = b_hh3[cj + 128];
    }
    if (wv < 8) {
        #pragma unroll
        for (int g = 0; g < 3; ++g) {
            #pragma unroll
            for (int kt = 0; kt < 2; ++kt)
                b2x[g][kt] = loadB(w_ih2, g * 128 + cj2, 64, kt * 32 + lr * 8);
            #pragma unroll
            for (int kt = 0; kt < 4; ++kt)
                b2h[g][kt] = loadB(w_hh2, g * 128 + cj2, 128, kt * 32 + lr * 8);
        }
        bs2r = b_ih2[cj2] + b_hh2[cj2];
        bs2z = b_ih2[cj2 + 128] + b_hh2[cj2 + 128];
        bi2n = b_ih2[cj2 + 256]; bh2n = b_hh2[cj2 + 256];
    }

    // recurrent state: 2 cells per thread (tile rows 4lr, 4lr+2)
    float h1own[2] = {0, 0}, h2own[2] = {0, 0}, h3own[2] = {0, 0};
    float accd = 0.0f;

    // helper mapping: thread h -> (batch row p4b, output col p4jo)
    const int hq    = tid & 511;
    const int p4b   = hq & 7;
    const int p4jo  = hq >> 3;
    const int p4row = p4b * 2;

    // prologue: helpers stage x(t=0..7) into x8 buf0
    if (wv >= 8) {
        const int h = tid - 512;
        if (h < 48) {
            int r = h / 6, q = h - r * 6;
            float4 v = *(const float4*)(x + (size_t)(Bb + r) * T_SEQ * 3 + q * 4);
            *(float4*)(sm + L_X8 + r * 96 + q * 16) = v;
        }
    }

    __syncthreads();

    #pragma unroll 1
    for (int t = 0; t <= T_SEQ + 1; ++t) {
        // ================= Phase X =================
        // waves 0-3: L1(t); waves 4-7: L3(t-1); waves 8-15: dense1(t-2) k 0-3
        if (wv < 4) {
            if (t < T_SEQ) {
                const int curO = ((t + 1) & 1) * 2048, nxtO = (t & 1) * 2048;
                f16x8 ah0 = ldsA(sm, L_H1S + curO, 128, lc, lr * 16);
                f16x8 ah1 = ldsA(sm, L_H1S + curO, 128, lc, 64 + lr * 16);
                f32x4 aR = {bs1r, bs1r, bs1r, bs1r};
                f32x4 aZ = {bs1z, bs1z, bs1z, bs1z};
                f32x4 aN = {bh1n, bh1n, bh1n, bh1n};
                __builtin_amdgcn_s_setprio(1);
                aR = mfma16(ah0, b1h[0][0], aR); aR = mfma16(ah1, b1h[0][1], aR);
                aZ = mfma16(ah0, b1h[1][0], aZ); aZ = mfma16(ah1, b1h[1][1], aZ);
                aN = mfma16(ah0, b1h[2][0], aN); aN = mfma16(ah1, b1h[2][1], aN);
                __builtin_amdgcn_s_setprio(0);
                const int xb = ((t >> 3) & 1) * 768, tt = (t & 7) * 12;
                #pragma unroll
                for (int ii = 0; ii < 2; ++ii) {
                    const int i = ii * 2, row = lr * 4 + i;
                    const float* xr = (const float*)(sm + L_X8 + xb + (2 * lr + ii) * 96 + tt);
                    float x0 = xr[0], x1 = xr[1], x2 = xr[2];
                    float xgr = wi1[0] * x0 + wi1[1] * x1 + wi1[2] * x2;
                    float xgz = wi1[3] * x0 + wi1[4] * x1 + wi1[5] * x2;
                    float xgn = wi1[6] * x0 + wi1[7] * x1 + wi1[8] * x2;
                    h1own[ii] = gru_cell(aR[i] + xgr, aZ[i] + xgz, xgn + bi1n, aN[i], h1own[ii]);
                    stH(sm, L_H1S + nxtO, 128, row, cj, (f16)h1own[ii]);
                    stH(sm, L_H1R, 128, row, cj, (f16)fmaxf(h1own[ii], 0.f));
                }
            }
        } else if (wv < 8) {
            if (t >= 1 && t <= T_SEQ) {   // L3(t-1)
                const int curO = (t & 1) * 2048, nxtO = ((t + 1) & 1) * 2048;
                f16x8 ax0 = ldsA(sm, L_H2R, 256, lc, lr * 16);
                f16x8 ax1 = ldsA(sm, L_H2R, 256, lc, 64 + lr * 16);
                f16x8 ax2 = ldsA(sm, L_H2R, 256, lc, 128 + lr * 16);
                f16x8 ax3 = ldsA(sm, L_H2R, 256, lc, 192 + lr * 16);
                f16x8 ah0 = ldsA(sm, L_H3S + curO, 128, lc, lr * 16);
                f16x8 ah1 = ldsA(sm, L_H3S + curO, 128, lc, 64 + lr * 16);
                f32x4 aR  = {bs3r, bs3r, bs3r, bs3r};
                f32x4 aZ  = {bs3z, bs3z, bs3z, bs3z};
                f32x4 aXn = {bi3n, bi3n, bi3n, bi3n};
                f32x4 aHn = {bh3n, bh3n, bh3n, bh3n};
                __builtin_amdgcn_s_setprio(1);
                aR = mfma16(ax0, b3x[0][0], aR); aR = mfma16(ax1, b3x[0][1], aR);
                aR = mfma16(ax2, b3x[0][2], aR); aR = mfma16(ax3, b3x[0][3], aR);
                aR = mfma16(ah0, b3h[0][0], aR); aR = mfma16(ah1, b3h[0][1], aR);
                aZ = mfma16(ax0, b3x[1][0], aZ); aZ = mfma16(ax1, b3x[1][1], aZ);
                aZ = mfma16(ax2, b3x[1][2], aZ); aZ = mfma16(ax3, b3x[1][3], aZ);
                aZ = mfma16(ah0, b3h[1][0], aZ); aZ = mfma16(ah1, b3h[1][1], aZ);
                aXn = mfma16(ax0, b3x[2][0], aXn); aXn = mfma16(ax1, b3x[2][1], aXn);
                aXn = mfma16(ax2, b3x[2][2], aXn); aXn = mfma16(ax3, b3x[2][3], aXn);
                aHn = mfma16(ah0, b3h[2][0], aHn); aHn = mfma16(ah1, b3h[2][1], aHn);
                __builtin_amdgcn_s_setprio(0);
                #pragma unroll
                for (int ii = 0; ii < 2; ++ii) {
                    const int i = ii * 2, row = lr * 4 + i;
                    h3own[ii] = gru_cell(aR[i], aZ[i], aXn[i], aHn[i], h3own[ii]);
                    stH(sm, L_H3S + nxtO, 128, row, cj, (f16)h3own[ii]);
                    stH(sm, L_H3R + nxtO, 128, row, cj, (f16)fmaxf(h3own[ii], 0.f));
                }
            }
        } else {
            if (t >= 2) {   // dense1(t-2), k-chunks 0-3
                const int rb = t & 1;
                #pragma unroll
                for (int i = 0; i < 4; ++i) {
                    int off = (L_H3R + rb * 2048 + p4row * 128 + i * 16) ^ ((p4row & 7) << 4);
                    f16x8 hv = *(const f16x8*)(sm + off);
                    if constexpr (W1H) {
                        f16x8 w8 = *(const f16x8*)(w1h + (size_t)p4jo * (T_SEQ * 64) + (size_t)(t - 2) * 64 + i * 8);
                        accd = dot8(hv, w8, accd);
                    } else {
                        const float* wp = w1 + (size_t)p4jo * (T_SEQ * 64) + (size_t)(t - 2) * 64 + i * 8;
                        float4 a = *(const float4*)wp;
                        float4 b = *(const float4*)(wp + 4);
                        accd += (float)hv[0] * a.x + (float)hv[1] * a.y + (float)hv[2] * a.z + (float)hv[3] * a.w
                              + (float)hv[4] * b.x + (float)hv[5] * b.y + (float)hv[6] * b.z + (float)hv[7] * b.w;
                    }
                }
            }
        }
        __syncthreads();

        // ================= Phase Y =================
        // waves 0-7: L2(t); waves 8-15: dense1(t-2) k 4-7 + x prefetch
        if (wv < 8) {
            if (t < T_SEQ) {
                const int curO = ((t + 1) & 1) * 4096, nxtO = (t & 1) * 4096;
                f16x8 ax0 = ldsA(sm, L_H1R, 128, lc, lr * 16);
                f16x8 ax1 = ldsA(sm, L_H1R, 128, lc, 64 + lr * 16);
                f16x8 ah0 = ldsA(sm, L_H2S + curO, 256, lc, lr * 16);
                f16x8 ah1 = ldsA(sm, L_H2S + curO, 256, lc, 64 + lr * 16);
                f16x8 ah2 = ldsA(sm, L_H2S + curO, 256, lc, 128 + lr * 16);
                f16x8 ah3 = ldsA(sm, L_H2S + curO, 256, lc, 192 + lr * 16);
                f32x4 aR  = {bs2r, bs2r, bs2r, bs2r};
                f32x4 aZ  = {bs2z, bs2z, bs2z, bs2z};
                f32x4 aXn = {bi2n, bi2n, bi2n, bi2n};
                f32x4 aHn = {bh2n, bh2n, bh2n, bh2n};
                __builtin_amdgcn_s_setprio(1);
                aR = mfma16(ax0, b2x[0][0], aR); aR = mfma16(ax1, b2x[0][1], aR);
                aR = mfma16(ah0, b2h[0][0], aR); aR = mfma16(ah1, b2h[0][1], aR);
                aR = mfma16(ah2, b2h[0][2], aR); aR = mfma16(ah3, b2h[0][3], aR);
                aZ = mfma16(ax0, b2x[1][0], aZ); aZ = mfma16(ax1, b2x[1][1], aZ);
                aZ = mfma16(ah0, b2h[1][0], aZ); aZ = mfma16(ah1, b2h[1][1], aZ);
                aZ = mfma16(ah2, b2h[1][2], aZ); aZ = mfma16(ah3, b2h[1][3], aZ);
                aXn = mfma16(ax0, b2x[2][0], aXn); aXn = mfma16(ax1, b2x[2][1], aXn);
                aHn = mfma16(ah0, b2h[2][0], aHn); aHn = mfma16(ah1, b2h[2][1], aHn);
                aHn = mfma16(ah2, b2h[2][2], aHn); aHn = mfma16(ah3, b2h[2][3], aHn);
                __builtin_amdgcn_s_setprio(0);
                #pragma unroll
                for (int ii = 0; ii < 2; ++ii) {
                    const int i = ii * 2, row = lr * 4 + i;
                    h2own[ii] = gru_cell(aR[i], aZ[i], aXn[i], aHn[i], h2own[ii]);
                    stH(sm, L_H2S + nxtO, 256, row, cj2, (f16)h2own[ii]);
                    stH(sm, L_H2R, 256, row, cj2, (f16)fmaxf(h2own[ii], 0.f));
                }
            }
        } else {
            if (t >= 2) {   // dense1(t-2), k-chunks 4-7
                const int rb = t & 1;
                #pragma unroll
                for (int i = 4; i < 8; ++i) {
                    int off = (L_H3R + rb * 2048 + p4row * 128 + i * 16) ^ ((p4row & 7) << 4);
                    f16x8 hv = *(const f16x8*)(sm + off);
                    if constexpr (W1H) {
                        f16x8 w8 = *(const f16x8*)(w1h + (size_t)p4jo * (T_SEQ * 64) + (size_t)(t - 2) * 64 + i * 8);
                        accd = dot8(hv, w8, accd);
                    } else {
                        const float* wp = w1 + (size_t)p4jo * (T_SEQ * 64) + (size_t)(t - 2) * 64 + i * 8;
                        float4 a = *(const float4*)wp;
                        float4 b = *(const float4*)(wp + 4);
                        accd += (float)hv[0] * a.x + (float)hv[1] * a.y + (float)hv[2] * a.z + (float)hv[3] * a.w
                              + (float)hv[4] * b.x + (float)hv[5] * b.y + (float)hv[6] * b.z + (float)hv[7] * b.w;
                    }
                }
            }
            // stage x for steps [t+8, t+16) every 8 steps
            if ((t & 7) == 0 && t + 8 < T_SEQ) {
                const int ts = t + 8;
                const int bufo = ((ts >> 3) & 1) * 768;
                const int h = tid - 512;
                if (ts + 8 <= T_SEQ) {
                    if (h < 48) {
                        int r = h / 6, q = h - r * 6;
                        float4 v = *(const float4*)(x + (size_t)(Bb + r) * T_SEQ * 3 + (size_t)ts * 3 + q * 4);
                        *(float4*)(sm + L_X8 + bufo + r * 96 + q * 16) = v;
                    }
                } else {
                    if (h < 192) {   // scalar tail with per-element bounds guard
                        int r = h / 24, e = h - r * 24;
                        int gt = ts + e / 3;
                        float v = (gt < T_SEQ) ? x[(size_t)(Bb + r) * T_SEQ * 3 + (size_t)gt * 3 + (e % 3)] : 0.f;
                        *(float*)(sm + L_X8 + bufo + r * 96 + e * 4) = v;
                    }
                }
            }
        }
        __syncthreads();
    }

    // ---------- head: dense1 bias+relu -> dense2 -> dense3 ----------
    float* o1 = (float*)sm;              // [8][68]
    if (wv >= 8) o1[p4b * 68 + p4jo] = fmaxf(accd + bd1[p4jo], 0.f);
    __syncthreads();
    float* o2 = (float*)(sm + 4096);     // [8][36]
    if (tid < 256) {
        const int bb = tid & 7, m = tid >> 3;
        float acc = bd2[m];
        const float* w2p = w2 + m * 64;
        const float* o1q = o1 + bb * 68;
        #pragma unroll
        for (int i = 0; i < 16; ++i) {
            float4 a = *(const float4*)(o1q + i * 4);
            float4 wv8 = *(const float4*)(w2p + i * 4);
            acc += a.x * wv8.x + a.y * wv8.y + a.z * wv8.z + a.w * wv8.w;
        }
        o2[bb * 36 + m] = fmaxf(acc, 0.f);
    }
    __syncthreads();
    for (int e = tid; e < 8 * 250; e += 1024) {
        const int bb = e / 250, p = e - bb * 250;
        float acc = bd3[p];
        const float* w3p = w3 + p * 32;
        const float* o2p = o2 + bb * 36;
        #pragma unroll
        for (int i = 0; i < 8; ++i) {
            float4 a = *(const float4*)(o2p + i * 4);
            float4 wv8 = *(const float4*)(w3p + i * 4);
            acc += a.x * wv8.x + a.y * wv8.y + a.z * wv8.z + a.w * wv8.w;
        }
        out[(size_t)(Bb + bb) * 250 + p] = fmaxf(acc, 0.f);
    }
}

extern "C" void kernel_launch(void* const* d_in, const int* in_sizes, int n_in,
                              void* d_out, int out_size, void* d_ws, size_t ws_size,
                              hipStream_t stream) {
    const float* x     = (const float*)d_in[0];
    const float* w_ih1 = (const float*)d_in[1];
    const float* w_hh1 = (const float*)d_in[2];
    const float* b_ih1 = (const float*)d_in[3];
    const float* b_hh1 = (const float*)d_in[4];
    const float* w_ih2 = (const float*)d_in[5];
    const float* w_hh2 = (const float*)d_in[6];
    const float* b_ih2 = (const float*)d_in[7];
    const float* b_hh2 = (const float*)d_in[8];
    const float* w_ih3 = (const float*)d_in[9];
    const float* w_hh3 = (const float*)d_in[10];
    const float* b_ih3 = (const float*)d_in[11];
    const float* b_hh3 = (const float*)d_in[12];
    const float* w1    = (const float*)d_in[13];
    const float* bd1   = (const float*)d_in[14];
    const float* w2    = (const float*)d_in[15];
    const float* bd2   = (const float*)d_in[16];
    const float* w3    = (const float*)d_in[17];
    const float* bd3   = (const float*)d_in[18];
    float* out = (float*)d_out;

    const int n1 = 64 * T_SEQ * 64;                 // w1 elements
    const bool useF16 = ws_size >= (size_t)n1 * sizeof(f16);
    f16* w1h = (f16*)d_ws;

    if (useF16) {
        hipLaunchKernelGGL(cvt_f16, dim3((n1 + 255) / 256), dim3(256), 0, stream, w1, w1h, n1);
        hipLaunchKernelGGL((gru_fused<true>), dim3(B_TOT / 8), dim3(1024), 0, stream,
                           x, w_ih1, w_hh1, b_ih1, b_hh1, w_ih2, w_hh2, b_ih2, b_hh2,
                           w_ih3, w_hh3, b_ih3, b_hh3,
                           w1h, w1, bd1, w2, bd2, w3, bd3, out);
    } else {
        hipLaunchKernelGGL((gru_fused<false>), dim3(B_TOT / 8), dim3(1024), 0, stream,
                           x, w_ih1, w_hh1, b_ih1, b_hh1, w_ih2, w_hh2, b_ih2, b_hh2,
                           w_ih3, w_hh3, b_ih3, b_hh3,
                           w1h, w1, bd1, w2, bd2, w3, bd3, out);
    }
}

// Round 9
// 2043.120 us; speedup vs baseline: 3.5978x; 3.5978x over previous
//
#include <hip/hip_runtime.h>

#define T_SEQ 543
#define B_TOT 2048

typedef _Float16 f16;
typedef f16   f16x8 __attribute__((ext_vector_type(8)));
typedef f16   f16x2 __attribute__((ext_vector_type(2)));
typedef float f32x4 __attribute__((ext_vector_type(4)));

#if defined(__has_builtin)
#if __has_builtin(__builtin_amdgcn_fdot2)
#define HAVE_FDOT2 1
#endif
#if __has_builtin(__builtin_amdgcn_rcpf)
#define RCP(x) __builtin_amdgcn_rcpf(x)
#endif
#endif
#ifndef RCP
#define RCP(x) (1.0f / (x))
#endif

__device__ __forceinline__ float sigm(float x)   { return RCP(1.0f + __expf(-x)); }
__device__ __forceinline__ float tanh_f(float x) { return fmaf(-2.0f, RCP(__expf(2.0f * x) + 1.0f), 1.0f); }

__device__ __forceinline__ f32x4 mfma16(f16x8 a, f16x8 b, f32x4 c) {
    return __builtin_amdgcn_mfma_f32_16x16x32_f16(a, b, c, 0, 0, 0);
}

__device__ __forceinline__ float dot2f(f16x2 a, f16x2 b, float c) {
#ifdef HAVE_FDOT2
    return __builtin_amdgcn_fdot2(a, b, c, false);
#else
    return c + (float)a.x * (float)b.x + (float)a.y * (float)b.y;
#endif
}

union U8 { f16x8 v; f16x2 h[4]; };
__device__ __forceinline__ float dot8(f16x8 a, f16x8 b, float c) {
    U8 A, B; A.v = a; B.v = b;
    c = dot2f(A.h[0], B.h[0], c); c = dot2f(A.h[1], B.h[1], c);
    c = dot2f(A.h[2], B.h[2], c); c = dot2f(A.h[3], B.h[3], c);
    return c;
}

// B-fragment: lane holds w[nrow][k0..k0+8) as f16x8 (row-major fp32 source)
__device__ __forceinline__ f16x8 loadB(const float* __restrict__ g, int nrow, int ldk, int k0) {
    const float* p = g + (size_t)nrow * ldk + k0;
    float4 a = *(const float4*)p;
    float4 b = *(const float4*)(p + 4);
    f16x8 r;
    r[0] = (f16)a.x; r[1] = (f16)a.y; r[2] = (f16)a.z; r[3] = (f16)a.w;
    r[4] = (f16)b.x; r[5] = (f16)b.y; r[6] = (f16)b.z; r[7] = (f16)b.w;
    return r;
}

// ---- LDS layout (bytes). Batch row r lives at tile row 2r; odd rows stay 0. ----
#define L_H1S 0        // 2 bufs x [16][64] f16 = 4096   (raw h1; buf[t&1] = h1(t))
#define L_H2S 4096     // 2 x [16][128]        = 8192    (raw h2; buf[t&1] = h2(t))
#define L_H3S 12288    // 2 x [16][64]         = 4096    (raw h3; buf[(t+1)&1] = h3(t))
#define L_H1R 16384    // [16][64]             = 2048    (relu h1(t))
#define L_H2R 18432    // [16][128]            = 4096    (relu h2(t))
#define L_H3R 22528    // 2 x [16][64]         = 4096    (relu h3; buf[t&1] = h3(t))
#define L_X1  26624    // [16] x 16B           = 256     (x(t) at even rows)
#define L_W2H 26880    // w_hh2 f16 [384 rows][128 k], swizzled = 98304
#define SMEM_T 125184

// XOR-swizzled LDS accessors (spread row-strided b128 reads over banks)
__device__ __forceinline__ f16x8 ldsA(const unsigned char* sm, int base, int stride, int row, int kByte) {
    int off = (base + row * stride + kByte) ^ ((row & 7) << 4);
    return *(const f16x8*)(sm + off);
}
__device__ __forceinline__ void stH(unsigned char* sm, int base, int stride, int row, int col, f16 v) {
    int off = (base + row * stride + col * 2) ^ ((row & 7) << 4);
    *(f16*)(sm + off) = v;
}

__global__ void cvt_f16(const float* __restrict__ s, f16* __restrict__ d, int n) {
    int i = blockIdx.x * 256 + threadIdx.x;
    if (i < n) d[i] = (f16)s[i];
}

// fused GRU gate; biases pre-folded into the accumulators
__device__ __forceinline__ float gru_cell(float aR, float aZ, float aXn, float aHn, float hprev) {
    float r = sigm(aR);
    float z = sigm(aZ);
    float n = tanh_f(aXn + r * aHn);
    return (1.f - z) * n + z * hprev;
}

template<bool W1H>
__global__ __launch_bounds__(512, 2) void gru_fused(
    const float* __restrict__ x,
    const float* __restrict__ w_ih1, const float* __restrict__ w_hh1,
    const float* __restrict__ b_ih1, const float* __restrict__ b_hh1,
    const float* __restrict__ w_ih2, const float* __restrict__ w_hh2,
    const float* __restrict__ b_ih2, const float* __restrict__ b_hh2,
    const float* __restrict__ w_ih3, const float* __restrict__ w_hh3,
    const float* __restrict__ b_ih3, const float* __restrict__ b_hh3,
    const f16* __restrict__ w1h, const float* __restrict__ w1, const float* __restrict__ bd1,
    const float* __restrict__ w2, const float* __restrict__ bd2,
    const float* __restrict__ w3, const float* __restrict__ bd3,
    float* __restrict__ out)
{
    __shared__ __align__(16) unsigned char sm[SMEM_T];
    const int tid = threadIdx.x;
    const int Bb  = blockIdx.x * 8;   // 8 batch rows per block
    const int wv  = tid >> 6;         // wave 0..7
    const int l   = tid & 63;
    const int lc  = l & 15;           // col index within fragment
    const int lr  = l >> 4;           // k-group; owns tile rows 4lr, 4lr+2

    // zero dynamic-state LDS (odd/pad rows must stay zero forever); W2H is
    // fully overwritten by staging below, so it needs no pre-zero.
    for (int e = tid * 4; e < L_W2H; e += 512 * 4) *(float*)(sm + e) = 0.0f;
    // stage w_hh2 -> LDS f16, swizzled to match ldsA(stride=256)
    for (int e = tid; e < 384 * 16; e += 512) {
        const int n = e >> 4, kc = e & 15;
        f16x8 v = loadB(w_hh2, n, 128, kc * 8);
        const int off = (L_W2H + n * 256 + kc * 16) ^ ((n & 7) << 4);
        *(f16x8*)(sm + off) = v;
    }
    // stage x(t=0): batch row r -> tile row 2r
    if (tid < 24) {
        int row = tid / 3, c = tid - row * 3;
        *(float*)(sm + L_X1 + row * 32 + c * 4) = x[(size_t)(Bb + row) * T_SEQ * 3 + c];
    }

    // ---- persistent weight fragments in VGPRs (w_hh2 lives in LDS now) ----
    f16x8 b1h[3][2];               // waves 0-3: w_hh1 [192][64]
    f16x8 b3x[3][4], b3h[3][2];    // waves 4-7: w_ih3 [192][128], w_hh3 [192][64]
    f16x8 b2x[3][2];               // all waves: w_ih2 [384][64]
    float wi1[9];
    float bs1r = 0, bs1z = 0, bi1n = 0, bh1n = 0;
    float bs3r = 0, bs3z = 0, bi3n = 0, bh3n = 0;

    const int cj = (wv & 3) * 16 + lc;    // h-col for L1/L3 phases
    if (wv < 4) {
        #pragma unroll
        for (int g = 0; g < 3; ++g)
            #pragma unroll
            for (int kt = 0; kt < 2; ++kt)
                b1h[g][kt] = loadB(w_hh1, g * 64 + cj, 64, kt * 32 + lr * 8);
        bs1r = b_ih1[cj] + b_hh1[cj];
        bs1z = b_ih1[cj + 64] + b_hh1[cj + 64];
        bi1n = b_ih1[cj + 128]; bh1n = b_hh1[cj + 128];
        #pragma unroll
        for (int g = 0; g < 3; ++g)
            #pragma unroll
            for (int i = 0; i < 3; ++i) wi1[g * 3 + i] = w_ih1[(cj + g * 64) * 3 + i];
    } else {
        #pragma unroll
        for (int g = 0; g < 3; ++g) {
            #pragma unroll
            for (int kt = 0; kt < 4; ++kt)
                b3x[g][kt] = loadB(w_ih3, g * 64 + cj, 128, kt * 32 + lr * 8);
            #pragma unroll
            for (int kt = 0; kt < 2; ++kt)
                b3h[g][kt] = loadB(w_hh3, g * 64 + cj, 64, kt * 32 + lr * 8);
        }
        bs3r = b_ih3[cj] + b_hh3[cj];
        bs3z = b_ih3[cj + 64] + b_hh3[cj + 64];
        bi3n = b_ih3[cj + 128]; bh3n = b_hh3[cj + 128];
    }
    const int cj2 = wv * 16 + lc;         // h-col for L2 phase
    #pragma unroll
    for (int g = 0; g < 3; ++g)
        #pragma unroll
        for (int kt = 0; kt < 2; ++kt)
            b2x[g][kt] = loadB(w_ih2, g * 128 + cj2, 64, kt * 32 + lr * 8);
    const float bs2r = b_ih2[cj2] + b_hh2[cj2];
    const float bs2z = b_ih2[cj2 + 128] + b_hh2[cj2 + 128];
    const float bi2n = b_ih2[cj2 + 256], bh2n = b_hh2[cj2 + 256];

    // recurrent state: 2 cells per thread (tile rows 4lr, 4lr+2)
    float h1own[2] = {0, 0}, h2own[2] = {0, 0}, h3own[2] = {0, 0};
    float accd = 0.0f;

    // dense1 pair: waves 0-3 -> (b=tid&7, jo 0..31) in phase X;
    //              waves 4-7 -> (b, jo 32..63) in phase Y.
    const int p4q   = tid & 255;
    const int p4b   = p4q & 7;
    const int p4jo  = (p4q >> 3) + ((wv >= 4) ? 32 : 0);
    const int p4row = p4b * 2;

    __syncthreads();

    #pragma unroll 1
    for (int t = 0; t <= T_SEQ + 1; ++t) {
        // ================= Phase X =================
        // waves 0-3: L1(t) + dense1(t-2);  waves 4-7: L3(t-1)
        if (wv < 4) {
            if (t < T_SEQ) {
                const int curO = ((t + 1) & 1) * 2048, nxtO = (t & 1) * 2048;
                f16x8 ah0 = ldsA(sm, L_H1S + curO, 128, lc, lr * 16);
                f16x8 ah1 = ldsA(sm, L_H1S + curO, 128, lc, 64 + lr * 16);
                f32x4 aR = {bs1r, bs1r, bs1r, bs1r};
                f32x4 aZ = {bs1z, bs1z, bs1z, bs1z};
                f32x4 aN = {bh1n, bh1n, bh1n, bh1n};
                __builtin_amdgcn_s_setprio(1);
                aR = mfma16(ah0, b1h[0][0], aR); aR = mfma16(ah1, b1h[0][1], aR);
                aZ = mfma16(ah0, b1h[1][0], aZ); aZ = mfma16(ah1, b1h[1][1], aZ);
                aN = mfma16(ah0, b1h[2][0], aN); aN = mfma16(ah1, b1h[2][1], aN);
                __builtin_amdgcn_s_setprio(0);
                #pragma unroll
                for (int ii = 0; ii < 2; ++ii) {
                    const int i = ii * 2, row = lr * 4 + i;
                    float4 xv = *(const float4*)(sm + L_X1 + row * 16);
                    float xgr = wi1[0] * xv.x + wi1[1] * xv.y + wi1[2] * xv.z;
                    float xgz = wi1[3] * xv.x + wi1[4] * xv.y + wi1[5] * xv.z;
                    float xgn = wi1[6] * xv.x + wi1[7] * xv.y + wi1[8] * xv.z;
                    h1own[ii] = gru_cell(aR[i] + xgr, aZ[i] + xgz, xgn + bi1n, aN[i], h1own[ii]);
                    stH(sm, L_H1S + nxtO, 128, row, cj, (f16)h1own[ii]);
                    stH(sm, L_H1R, 128, row, cj, (f16)fmaxf(h1own[ii], 0.f));
                }
            }
            if (t >= 2) {   // dense1(t-2), jo 0..31
                const int rb = t & 1;
                #pragma unroll
                for (int i = 0; i < 8; ++i) {
                    int off = (L_H3R + rb * 2048 + p4row * 128 + i * 16) ^ ((p4row & 7) << 4);
                    f16x8 hv = *(const f16x8*)(sm + off);
                    if constexpr (W1H) {
                        f16x8 w8 = *(const f16x8*)(w1h + (size_t)p4jo * (T_SEQ * 64) + (size_t)(t - 2) * 64 + i * 8);
                        accd = dot8(hv, w8, accd);
                    } else {
                        const float* wp = w1 + (size_t)p4jo * (T_SEQ * 64) + (size_t)(t - 2) * 64 + i * 8;
                        float4 a = *(const float4*)wp;
                        float4 b = *(const float4*)(wp + 4);
                        accd += (float)hv[0] * a.x + (float)hv[1] * a.y + (float)hv[2] * a.z + (float)hv[3] * a.w
                              + (float)hv[4] * b.x + (float)hv[5] * b.y + (float)hv[6] * b.z + (float)hv[7] * b.w;
                    }
                }
            }
        } else {
            if (t >= 1 && t <= T_SEQ) {   // L3(t-1)
                const int curO = (t & 1) * 2048, nxtO = ((t + 1) & 1) * 2048;
                f16x8 ax0 = ldsA(sm, L_H2R, 256, lc, lr * 16);
                f16x8 ax1 = ldsA(sm, L_H2R, 256, lc, 64 + lr * 16);
                f16x8 ax2 = ldsA(sm, L_H2R, 256, lc, 128 + lr * 16);
                f16x8 ax3 = ldsA(sm, L_H2R, 256, lc, 192 + lr * 16);
                f16x8 ah0 = ldsA(sm, L_H3S + curO, 128, lc, lr * 16);
                f16x8 ah1 = ldsA(sm, L_H3S + curO, 128, lc, 64 + lr * 16);
                f32x4 aR  = {bs3r, bs3r, bs3r, bs3r};
                f32x4 aZ  = {bs3z, bs3z, bs3z, bs3z};
                f32x4 aXn = {bi3n, bi3n, bi3n, bi3n};
                f32x4 aHn = {bh3n, bh3n, bh3n, bh3n};
                __builtin_amdgcn_s_setprio(1);
                aR = mfma16(ax0, b3x[0][0], aR); aR = mfma16(ax1, b3x[0][1], aR);
                aR = mfma16(ax2, b3x[0][2], aR); aR = mfma16(ax3, b3x[0][3], aR);
                aR = mfma16(ah0, b3h[0][0], aR); aR = mfma16(ah1, b3h[0][1], aR);
                aZ = mfma16(ax0, b3x[1][0], aZ); aZ = mfma16(ax1, b3x[1][1], aZ);
                aZ = mfma16(ax2, b3x[1][2], aZ); aZ = mfma16(ax3, b3x[1][3], aZ);
                aZ = mfma16(ah0, b3h[1][0], aZ); aZ = mfma16(ah1, b3h[1][1], aZ);
                aXn = mfma16(ax0, b3x[2][0], aXn); aXn = mfma16(ax1, b3x[2][1], aXn);
                aXn = mfma16(ax2, b3x[2][2], aXn); aXn = mfma16(ax3, b3x[2][3], aXn);
                aHn = mfma16(ah0, b3h[2][0], aHn); aHn = mfma16(ah1, b3h[2][1], aHn);
                __builtin_amdgcn_s_setprio(0);
                #pragma unroll
                for (int ii = 0; ii < 2; ++ii) {
                    const int i = ii * 2, row = lr * 4 + i;
                    h3own[ii] = gru_cell(aR[i], aZ[i], aXn[i], aHn[i], h3own[ii]);
                    stH(sm, L_H3S + nxtO, 128, row, cj, (f16)h3own[ii]);
                    stH(sm, L_H3R + nxtO, 128, row, cj, (f16)fmaxf(h3own[ii], 0.f));
                }
            }
        }
        __syncthreads();

        // ================= Phase Y: L2(t) on all 8 waves =================
        if (t < T_SEQ) {
            const int curO = ((t + 1) & 1) * 4096, nxtO = (t & 1) * 4096;
            const int kb = lr * 16;
            f16x8 ax0 = ldsA(sm, L_H1R, 128, lc, kb);
            f16x8 ax1 = ldsA(sm, L_H1R, 128, lc, 64 + kb);
            f16x8 ah0 = ldsA(sm, L_H2S + curO, 256, lc, kb);
            f16x8 ah1 = ldsA(sm, L_H2S + curO, 256, lc, 64 + kb);
            f16x8 ah2 = ldsA(sm, L_H2S + curO, 256, lc, 128 + kb);
            f16x8 ah3 = ldsA(sm, L_H2S + curO, 256, lc, 192 + kb);
            // w_hh2 B-fragments from LDS (shared across waves)
            f16x8 wr0 = ldsA(sm, L_W2H, 256, cj2,       kb);
            f16x8 wr1 = ldsA(sm, L_W2H, 256, cj2,  64 + kb);
            f16x8 wr2 = ldsA(sm, L_W2H, 256, cj2, 128 + kb);
            f16x8 wr3 = ldsA(sm, L_W2H, 256, cj2, 192 + kb);
            f16x8 wz0 = ldsA(sm, L_W2H, 256, 128 + cj2,       kb);
            f16x8 wz1 = ldsA(sm, L_W2H, 256, 128 + cj2,  64 + kb);
            f16x8 wz2 = ldsA(sm, L_W2H, 256, 128 + cj2, 128 + kb);
            f16x8 wz3 = ldsA(sm, L_W2H, 256, 128 + cj2, 192 + kb);
            f16x8 wn0 = ldsA(sm, L_W2H, 256, 256 + cj2,       kb);
            f16x8 wn1 = ldsA(sm, L_W2H, 256, 256 + cj2,  64 + kb);
            f16x8 wn2 = ldsA(sm, L_W2H, 256, 256 + cj2, 128 + kb);
            f16x8 wn3 = ldsA(sm, L_W2H, 256, 256 + cj2, 192 + kb);
            f32x4 aR  = {bs2r, bs2r, bs2r, bs2r};
            f32x4 aZ  = {bs2z, bs2z, bs2z, bs2z};
            f32x4 aXn = {bi2n, bi2n, bi2n, bi2n};
            f32x4 aHn = {bh2n, bh2n, bh2n, bh2n};
            __builtin_amdgcn_s_setprio(1);
            aR = mfma16(ax0, b2x[0][0], aR); aR = mfma16(ax1, b2x[0][1], aR);
            aR = mfma16(ah0, wr0, aR); aR = mfma16(ah1, wr1, aR);
            aR = mfma16(ah2, wr2, aR); aR = mfma16(ah3, wr3, aR);
            aZ = mfma16(ax0, b2x[1][0], aZ); aZ = mfma16(ax1, b2x[1][1], aZ);
            aZ = mfma16(ah0, wz0, aZ); aZ = mfma16(ah1, wz1, aZ);
            aZ = mfma16(ah2, wz2, aZ); aZ = mfma16(ah3, wz3, aZ);
            aXn = mfma16(ax0, b2x[2][0], aXn); aXn = mfma16(ax1, b2x[2][1], aXn);
            aHn = mfma16(ah0, wn0, aHn); aHn = mfma16(ah1, wn1, aHn);
            aHn = mfma16(ah2, wn2, aHn); aHn = mfma16(ah3, wn3, aHn);
            __builtin_amdgcn_s_setprio(0);
            #pragma unroll
            for (int ii = 0; ii < 2; ++ii) {
                const int i = ii * 2, row = lr * 4 + i;
                h2own[ii] = gru_cell(aR[i], aZ[i], aXn[i], aHn[i], h2own[ii]);
                stH(sm, L_H2S + nxtO, 256, row, cj2, (f16)h2own[ii]);
                stH(sm, L_H2R, 256, row, cj2, (f16)fmaxf(h2own[ii], 0.f));
            }
        }
        if (wv >= 4 && t >= 2) {   // dense1(t-2), jo 32..63
            const int rb = t & 1;
            #pragma unroll
            for (int i = 0; i < 8; ++i) {
                int off = (L_H3R + rb * 2048 + p4row * 128 + i * 16) ^ ((p4row & 7) << 4);
                f16x8 hv = *(const f16x8*)(sm + off);
                if constexpr (W1H) {
                    f16x8 w8 = *(const f16x8*)(w1h + (size_t)p4jo * (T_SEQ * 64) + (size_t)(t - 2) * 64 + i * 8);
                    accd = dot8(hv, w8, accd);
                } else {
                    const float* wp = w1 + (size_t)p4jo * (T_SEQ * 64) + (size_t)(t - 2) * 64 + i * 8;
                    float4 a = *(const float4*)wp;
                    float4 b = *(const float4*)(wp + 4);
                    accd += (float)hv[0] * a.x + (float)hv[1] * a.y + (float)hv[2] * a.z + (float)hv[3] * a.w
                          + (float)hv[4] * b.x + (float)hv[5] * b.y + (float)hv[6] * b.z + (float)hv[7] * b.w;
                }
            }
        }
        if (wv < 4 && t + 1 < T_SEQ && tid < 24) {   // stage x(t+1)
            int row = tid / 3, c = tid - row * 3;
            *(float*)(sm + L_X1 + row * 32 + c * 4) =
                x[(size_t)(Bb + row) * T_SEQ * 3 + (size_t)(t + 1) * 3 + c];
        }
        __syncthreads();
    }

    // ---------- head: dense1 bias+relu -> dense2 -> dense3 ----------
    float* o1 = (float*)sm;              // [8][68]
    o1[p4b * 68 + p4jo] = fmaxf(accd + bd1[p4jo], 0.f);
    __syncthreads();
    float* o2 = (float*)(sm + 4096);     // [8][36]
    if (tid < 256) {
        const int bb = tid & 7, m = tid >> 3;
        float acc = bd2[m];
        const float* w2p = w2 + m * 64;
        const float* o1q = o1 + bb * 68;
        #pragma unroll
        for (int i = 0; i < 16; ++i) {
            float4 a = *(const float4*)(o1q + i * 4);
            float4 wv8 = *(const float4*)(w2p + i * 4);
            acc += a.x * wv8.x + a.y * wv8.y + a.z * wv8.z + a.w * wv8.w;
        }
        o2[bb * 36 + m] = fmaxf(acc, 0.f);
    }
    __syncthreads();
    for (int e = tid; e < 8 * 250; e += 512) {
        const int bb = e / 250, p = e - bb * 250;
        float acc = bd3[p];
        const float* w3p = w3 + p * 32;
        const float* o2p = o2 + bb * 36;
        #pragma unroll
        for (int i = 0; i < 8; ++i) {
            float4 a = *(const float4*)(o2p + i * 4);
            float4 wv8 = *(const float4*)(w3p + i * 4);
            acc += a.x * wv8.x + a.y * wv8.y + a.z * wv8.z + a.w * wv8.w;
        }
        out[(size_t)(Bb + bb) * 250 + p] = fmaxf(acc, 0.f);
    }
}

extern "C" void kernel_launch(void* const* d_in, const int* in_sizes, int n_in,
                              void* d_out, int out_size, void* d_ws, size_t ws_size,
                              hipStream_t stream) {
    const float* x     = (const float*)d_in[0];
    const float* w_ih1 = (const float*)d_in[1];
    const float* w_hh1 = (const float*)d_in[2];
    const float* b_ih1 = (const float*)d_in[3];
    const float* b_hh1 = (const float*)d_in[4];
    const float* w_ih2 = (const float*)d_in[5];
    const float* w_hh2 = (const float*)d_in[6];
    const float* b_ih2 = (const float*)d_in[7];
    const float* b_hh2 = (const float*)d_in[8];
    const float* w_ih3 = (const float*)d_in[9];
    const float* w_hh3 = (const float*)d_in[10];
    const float* b_ih3 = (const float*)d_in[11];
    const float* b_hh3 = (const float*)d_in[12];
    const float* w1    = (const float*)d_in[13];
    const float* bd1   = (const float*)d_in[14];
    const float* w2    = (const float*)d_in[15];
    const float* bd2   = (const float*)d_in[16];
    const float* w3    = (const float*)d_in[17];
    const float* bd3   = (const float*)d_in[18];
    float* out = (float*)d_out;

    const int n1 = 64 * T_SEQ * 64;                 // w1 elements
    const bool useF16 = ws_size >= (size_t)n1 * sizeof(f16);
    f16* w1h = (f16*)d_ws;

    if (useF16) {
        hipLaunchKernelGGL(cvt_f16, dim3((n1 + 255) / 256), dim3(256), 0, stream, w1, w1h, n1);
        hipLaunchKernelGGL((gru_fused<true>), dim3(B_TOT / 8), dim3(512), 0, stream,
                           x, w_ih1, w_hh1, b_ih1, b_hh1, w_ih2, w_hh2, b_ih2, b_hh2,
                           w_ih3, w_hh3, b_ih3, b_hh3,
                           w1h, w1, bd1, w2, bd2, w3, bd3, out);
    } else {
        hipLaunchKernelGGL((gru_fused<false>), dim3(B_TOT / 8), dim3(512), 0, stream,
                           x, w_ih1, w_hh1, b_ih1, b_hh1, w_ih2, w_hh2, b_ih2, b_hh2,
                           w_ih3, w_hh3, b_ih3, b_hh3,
                           w1h, w1, bd1, w2, bd2, w3, bd3, out);
    }
}